// Round 20
// baseline (2265.927 us; speedup 1.0000x reference)
//
#include <hip/hip_runtime.h>
#include <hip/hip_cooperative_groups.h>
#include <stdint.h>

namespace cg = cooperative_groups;

// ====== TrajectoryLSTM r20 — byte-identical revert to r16 (best: 2241 us) ======
#define Bsz   16384
#define Tseq  8
#define NPRED 12

typedef __attribute__((ext_vector_type(4))) float    f32x4;
typedef _Float16 h16;
typedef __attribute__((ext_vector_type(8))) _Float16 h16x8;

__device__ __forceinline__ float sigf(float x)   { return 1.f / (1.f + __expf(-x)); }
__device__ __forceinline__ float tanh_f(float x) { return 1.f - 2.f / (__expf(2.f * x) + 1.f); }

__device__ __forceinline__ void gload_lds16(const void* g, void* l) {
  __builtin_amdgcn_global_load_lds(
      (const __attribute__((address_space(1))) void*)g,
      (__attribute__((address_space(3))) void*)l, 16, 0, 0);
}

__global__ void mark_r16(float* __restrict__ out) {
  if (blockIdx.x == 0 && threadIdx.x < 64) out[threadIdx.x] = 1000.0f;
}

// ---- weight packing (device fn): slab-major [nb*KB+kb] blocks of [256 r][64 k]
// (32KB), XOR-preswizzled rows; gatePack: r -> n = gi*256 + nb*64 + wc*16 + jr.
__device__ __forceinline__ void pack_one(h16* dst, const float* W0, const float* W1,
                                         int ksplit, int Kw, int idx, int gatePack) {
  int np = idx / Kw, k = idx - np * Kw;
  int nb = np >> 8, r = np & 255;
  int n = np;
  if (gatePack) {
    int wcq = r >> 6, gi = (r >> 4) & 3, jr = r & 15;
    n = gi * 256 + nb * 64 + wcq * 16 + jr;
  }
  float w = (k < ksplit) ? W0[(size_t)n * ksplit + k]
                         : W1[(size_t)n * (Kw - ksplit) + (k - ksplit)];
  int KB = Kw >> 6, kb = k >> 6;
  uint32_t byte = (uint32_t)(nb * KB + kb) * 32768u + (uint32_t)r * 128u
                + ((2u * (uint32_t)(k & 63)) ^ (uint32_t)((r & 7) << 4));
  *(h16*)((char*)dst + byte) = (h16)w;
}

// ---- fused setup: all weight packs + bias sums + pos seed + L1.l0@t=0 pointwise ----
#define SO1 262144
#define SO2 786432
#define SO3 1310720
#define SO4 1835008
#define SO5 1900544
#define SO6 1904640
#define SO7 1921024
#define SO8 2445312

struct SetupArgs {
  h16 *wp10, *wp0, *wp1, *wp2, *wpf1;
  float* biasc;
  const float *Whh0, *Wih1, *Whh1, *Wih2, *Whh2, *Wih3, *Whh3, *fc1w;
  const float *bih0, *bhh0, *bih1, *bhh1, *bih2, *bhh2, *bih3, *bhh3;
  const float *x, *Wih0;
  float* pos;
  h16* C0; char* h00;
};

__global__ void setup_all(SetupArgs s) {
  int gid = blockIdx.x * 256 + threadIdx.x;
  if (gid < SO1) {
    pack_one(s.wp10, s.Whh0, s.Whh0, 256, 256, gid, 1);
  } else if (gid < SO2) {
    pack_one(s.wp0, s.Wih1, s.Whh1, 256, 512, gid - SO1, 1);
  } else if (gid < SO3) {
    pack_one(s.wp1, s.Wih2, s.Whh2, 256, 512, gid - SO2, 1);
  } else if (gid < SO4) {
    pack_one(s.wp2, s.Wih3, s.Whh3, 256, 512, gid - SO3, 1);
  } else if (gid < SO5) {
    pack_one(s.wpf1, s.fc1w, s.fc1w, 256, 256, gid - SO4, 0);
  } else if (gid < SO6) {
    int i = gid - SO5;
    int l = i >> 10, j = i & 1023;
    const float* bi_[4] = {s.bih0, s.bih1, s.bih2, s.bih3};
    const float* bh_[4] = {s.bhh0, s.bhh1, s.bhh2, s.bhh3};
    s.biasc[i] = bi_[l][j] + bh_[l][j];
  } else if (gid < SO7) {
    int b = gid - SO6;
    s.pos[2 * b]     = s.x[(size_t)b * 16 + 14];
    s.pos[2 * b + 1] = s.x[(size_t)b * 16 + 15];
  } else if (gid < SO8) {
    int t = gid - SO7;
    int b = t >> 5, jb = (t & 31) << 3;
    float x0 = s.x[(size_t)b * 16], x1 = s.x[(size_t)b * 16 + 1];
    h16 cc[8], hh[8];
#pragma unroll
    for (int q = 0; q < 8; ++q) {
      int j = jb + q;
      float vi = s.bih0[j]       + s.bhh0[j]       + x0 * s.Wih0[2 * j]         + x1 * s.Wih0[2 * j + 1];
      float vg = s.bih0[512 + j] + s.bhh0[512 + j] + x0 * s.Wih0[2 * (512 + j)] + x1 * s.Wih0[2 * (512 + j) + 1];
      float vo = s.bih0[768 + j] + s.bhh0[768 + j] + x0 * s.Wih0[2 * (768 + j)] + x1 * s.Wih0[2 * (768 + j) + 1];
      float cn = sigf(vi) * tanh_f(vg);
      hh[q] = (h16)(sigf(vo) * tanh_f(cn));
      cc[q] = (h16)cn;
    }
    *(h16x8*)(s.C0 + (size_t)b * 256 + jb) = *(h16x8*)cc;
    *(h16x8*)(s.h00 + (size_t)b * 512 + (((unsigned)jb * 2) ^ (unsigned)((b & 7) << 4))) = *(h16x8*)hh;
  }
}

// ---- GEMM core: 512 threads / 8 waves (2Mx4N), tile 128x256, BK=64 ----
// KBiter = K-slabs to process; KBpack = pack-time KB (slab-base stride).
__device__ __forceinline__ void gemm_core(
    const char* A0, const char* A1, const char* Wp, int KBiter, int KBpack,
    int by, int m0, char* lds, int tid, f32x4 acc[4][4]) {
  char* ldsA = lds;
  char* ldsB = lds + 16384;
  const int wave = tid >> 6, lane = tid & 63;
  const int wr = wave >> 2, wc = wave & 3;
  const int rowa = tid >> 3;          // 0..63
  const int chb  = (tid & 7) * 16;

#pragma unroll
  for (int m = 0; m < 4; m++)
#pragma unroll
    for (int n = 0; n < 4; n++)
#pragma unroll
      for (int e = 0; e < 4; e++) acc[m][n][e] = 0.f;

  const char* aCur   = A0 + (size_t)(m0 + rowa) * 512 + chb;
  const char* a1Base = A1 + (size_t)(m0 + rowa) * 512 + chb;
  const char* wCur   = Wp + (size_t)by * KBpack * 32768 + (size_t)tid * 16;

  for (int kb = 0; kb < KBiter; ++kb) {
    if (kb == 4) aCur = a1Base;       // K=512 segment switch (unreachable at KBiter==4)
    gload_lds16(aCur,          ldsA + wave * 1024);          // rows 0..63
    gload_lds16(aCur + 32768,  ldsA + 8192 + wave * 1024);   // rows 64..127
#pragma unroll
    for (int it = 0; it < 4; ++it)
      gload_lds16(wCur + it * 8192, ldsB + it * 8192 + wave * 1024);
    __syncthreads();
#pragma unroll
    for (int kk = 0; kk < 2; ++kk) {
      const int kbyte = kk * 64 + (lane >> 4) * 16;
      h16x8 af[4], bfr[4];
#pragma unroll
      for (int mt = 0; mt < 4; ++mt) {
        int r = wr * 64 + mt * 16 + (lane & 15);
        af[mt] = *(const h16x8*)(ldsA + r * 128 + (kbyte ^ ((r & 7) << 4)));
      }
#pragma unroll
      for (int nt = 0; nt < 4; ++nt) {
        int c = wc * 64 + nt * 16 + (lane & 15);
        bfr[nt] = *(const h16x8*)(ldsB + c * 128 + (kbyte ^ ((c & 7) << 4)));
      }
#pragma unroll
      for (int mt = 0; mt < 4; ++mt)
#pragma unroll
        for (int nt = 0; nt < 4; ++nt)
          acc[mt][nt] = __builtin_amdgcn_mfma_f32_16x16x32_f16(af[mt], bfr[nt], acc[mt][nt], 0, 0, 0);
    }
    __syncthreads();
    aCur += 128;
    wCur += 32768;
  }
}

// ---- LSTM epilogue: lane owns ONE j (= by*64 + wc*16 + lane&15); gates = nt ----
__device__ __forceinline__ void lstm_epilogue(
    f32x4 acc[4][4], int m0, int by, int tid, const float* bias,
    const float* wih0, const float* xbase, int xstride, int hasx, int skipc,
    h16* Cst, char* hout) {
  const int wave = tid >> 6, lane = tid & 63;
  const int wr = wave >> 2, wc = wave & 3;
  const int j = by * 64 + wc * 16 + (lane & 15);
  const float bi = bias[j], bff = bias[256 + j], bg = bias[512 + j], bo = bias[768 + j];
  float wi0 = 0, wi1 = 0, wf0 = 0, wf1 = 0, wg0 = 0, wg1 = 0, wo0 = 0, wo1 = 0;
  if (hasx) {
    wi0 = wih0[2 * j];           wi1 = wih0[2 * j + 1];
    wf0 = wih0[2 * (256 + j)];   wf1 = wih0[2 * (256 + j) + 1];
    wg0 = wih0[2 * (512 + j)];   wg1 = wih0[2 * (512 + j) + 1];
    wo0 = wih0[2 * (768 + j)];   wo1 = wih0[2 * (768 + j) + 1];
  }
#pragma unroll
  for (int mt = 0; mt < 4; ++mt) {
#pragma unroll
    for (int e = 0; e < 4; e++) {
      const int b = m0 + wr * 64 + mt * 16 + (lane >> 4) * 4 + e;
      float vi = acc[mt][0][e] + bi;
      float vf = acc[mt][1][e] + bff;
      float vg = acc[mt][2][e] + bg;
      float vo = acc[mt][3][e] + bo;
      if (hasx) {
        const float x0 = xbase[(size_t)b * xstride];
        const float x1 = xbase[(size_t)b * xstride + 1];
        vi += x0 * wi0 + x1 * wi1;
        vf += x0 * wf0 + x1 * wf1;
        vg += x0 * wg0 + x1 * wg1;
        vo += x0 * wo0 + x1 * wo1;
      }
      const size_t ci = (size_t)b * 256 + j;
      float cn = sigf(vi) * tanh_f(vg);
      if (!skipc) cn += sigf(vf) * (float)Cst[ci];
      float h = sigf(vo) * tanh_f(cn);
      Cst[ci] = (h16)cn;
      *(h16*)(hout + (size_t)b * 512 + (((unsigned)j * 2) ^ (unsigned)((b & 7) << 4))) = (h16)h;
    }
  }
}

// ---- fused fc1+relu+fc2+pos body: ONE K=256 N=256 GEMM + strip + dot ----
__device__ __forceinline__ void head_body(
    const char* A, const char* Wp, const float* b1, const float* w2,
    const float* b2, float* pos, float* out, int s, int blk, int tid, char* lds) {
  const int m0 = blk * 128;
  const int wave = tid >> 6, lane = tid & 63;
  const int wr = wave >> 2, wc = wave & 3;

  f32x4 acc[4][4];
  gemm_core(A, A, Wp, 4, 4, 0, m0, lds, tid, acc);

  h16* strip = (h16*)lds;    // [128][262] fp16 = 67072 B
#pragma unroll
  for (int nt = 0; nt < 4; ++nt) {
    const int n = wc * 64 + nt * 16 + (lane & 15);
    const float bn = b1[n];
#pragma unroll
    for (int mt = 0; mt < 4; ++mt)
#pragma unroll
      for (int e = 0; e < 4; e++) {
        const int bl = wr * 64 + mt * 16 + (lane >> 4) * 4 + e;
        float v = acc[mt][nt][e] + bn;
        strip[bl * 262 + n] = (h16)(v > 0.f ? v : 0.f);
      }
  }
  __syncthreads();
  if (tid < 256) {
    const int bl2 = tid >> 1, comp = tid & 1;
    const float* wrow = w2 + comp * 256;
    float a = 0.f;
#pragma unroll 8
    for (int n = 0; n < 256; ++n)
      a += (float)strip[bl2 * 262 + n] * wrow[n];
    const size_t b = (size_t)(m0 + bl2);
    float p = pos[2 * b + comp] + a + b2[comp];
    pos[2 * b + comp] = p;
    out[b * (NPRED * 2) + s * 2 + comp] = p;
  }
  __syncthreads();
}

// ---- per-cell descriptor (encoder diagonals) ----
struct CellDesc {
  const char* A0; const char* A1; const char* Wp;
  const float* bias; const float* wih0; const float* xbase;
  h16* Cst; char* hout;
  int KBiter; int KBpack; int xstride; int hasx; int skipc;
};
struct Fused4 { CellDesc c[4]; };

__global__ __launch_bounds__(512, 4) void cells_diag(Fused4 args) {
  const int cellid = blockIdx.x >> 9;
  const int lid    = blockIdx.x & 511;
  const CellDesc d = args.c[cellid];

  __shared__ __align__(16) char lds[49152];
  const int tid = threadIdx.x;

  int swz = (lid & 7) * 64 + (lid >> 3);
  const int by = swz & 3, bx = swz >> 2;   // NY = 4
  const int m0 = bx * 128;

  f32x4 acc[4][4];
  gemm_core(d.A0, d.A1, d.Wp, d.KBiter, d.KBpack, by, m0, lds, tid, acc);
  lstm_epilogue(acc, m0, by, tid, d.bias, d.wih0, d.xbase, d.xstride, d.hasx,
                d.skipc, d.Cst, d.hout);
}

// ---- decoder args + cooperative persistent kernel (512 blocks = 2/CU) ----
struct DecArgs {
  char* hb0[2]; char* hb1[2]; char* hb2[2]; char* hb3[2];
  h16* Cs0; h16* Cs1; h16* Cs2; h16* Cs3;
  const char* wp10; const char* wp0; const char* wp1; const char* wp2; const char* wpf1;
  const float* biasc; const float* wih0;
  const float* fc1_b; const float* fc2_w; const float* fc2_b;
  float* pos; float* out;
};

__global__ __launch_bounds__(512, 4) void decoder_coop(DecArgs a) {
  cg::grid_group grid = cg::this_grid();
  __shared__ __align__(16) char lds[67072];
  const int tid = threadIdx.x;
  const int lid = blockIdx.x;
  int swz = (lid & 7) * 64 + (lid >> 3);
  const int by = swz & 3, bx = swz >> 2;
  const int m0 = bx * 128;

  for (int s = 0; s < NPRED; ++s) {
    const int u = Tseq + s, cur = u & 1, prev = cur ^ 1;
    {  // L1.l0 (K=256, x-part = pos in epilogue)
      f32x4 acc[4][4];
      gemm_core(a.hb0[prev], a.hb0[prev], a.wp10, 4, 4, by, m0, lds, tid, acc);
      lstm_epilogue(acc, m0, by, tid, a.biasc, a.wih0, a.pos, 2, 1, 0, a.Cs0, a.hb0[cur]);
    }
    __threadfence();  grid.sync();
    {  // L1.l1 (K=512)
      f32x4 acc[4][4];
      gemm_core(a.hb0[cur], a.hb1[prev], a.wp0, 8, 8, by, m0, lds, tid, acc);
      lstm_epilogue(acc, m0, by, tid, a.biasc + 1024, nullptr, nullptr, 0, 0, 0, a.Cs1, a.hb1[cur]);
    }
    __threadfence();  grid.sync();
    {  // L2.l0 (K=512)
      f32x4 acc[4][4];
      gemm_core(a.hb1[cur], a.hb2[prev], a.wp1, 8, 8, by, m0, lds, tid, acc);
      lstm_epilogue(acc, m0, by, tid, a.biasc + 2048, nullptr, nullptr, 0, 0, 0, a.Cs2, a.hb2[cur]);
    }
    __threadfence();  grid.sync();
    {  // L2.l1 (K=512)
      f32x4 acc[4][4];
      gemm_core(a.hb2[cur], a.hb3[prev], a.wp2, 8, 8, by, m0, lds, tid, acc);
      lstm_epilogue(acc, m0, by, tid, a.biasc + 3072, nullptr, nullptr, 0, 0, 0, a.Cs3, a.hb3[cur]);
    }
    __threadfence();  grid.sync();
    if (lid < 128)
      head_body(a.hb3[cur], a.wpf1, a.fc1_b, a.fc2_w, a.fc2_b, a.pos, a.out, s, lid, tid, lds);
    __threadfence();  grid.sync();
  }
}

// ---- fallback decoder kernels ----
template <int NSEG, int HASX>
__global__ __launch_bounds__(512, 4) void cell_gemm(
    const char* __restrict__ A0, const char* __restrict__ A1,
    const char* __restrict__ Wp, int Kw,
    const float* __restrict__ bias, const float* __restrict__ wih0,
    const float* __restrict__ xbase, int xstride,
    h16* __restrict__ Cst, char* __restrict__ hout) {
  __shared__ __align__(16) char lds[49152];
  const int tid = threadIdx.x;
  int lid = blockIdx.x;
  int swz = (lid & 7) * 64 + (lid >> 3);
  const int by = swz & 3, bx = swz >> 2;
  const int m0 = bx * 128;
  f32x4 acc[4][4];
  gemm_core(A0, NSEG == 2 ? A1 : A0, Wp, Kw >> 6, Kw >> 6, by, m0, lds, tid, acc);
  lstm_epilogue(acc, m0, by, tid, bias, wih0, xbase, xstride, HASX, 0, Cst, hout);
}

__global__ __launch_bounds__(512) void fc_head(
    const char* __restrict__ A, const char* __restrict__ Wp,
    const float* __restrict__ b1, const float* __restrict__ w2,
    const float* __restrict__ b2, float* __restrict__ pos,
    float* __restrict__ out, int s) {
  __shared__ __align__(16) char lds[67072];
  head_body(A, Wp, b1, w2, b2, pos, out, s, blockIdx.x, threadIdx.x, lds);
}

// ---------- host ----------
extern "C" void kernel_launch(void* const* d_in, const int* in_sizes, int n_in,
                              void* d_out, int out_size, void* d_ws, size_t ws_size,
                              hipStream_t stream) {
  const float* x      = (const float*)d_in[0];
  const float* Wih[4] = {(const float*)d_in[1], (const float*)d_in[5],
                         (const float*)d_in[9], (const float*)d_in[13]};
  const float* Whh[4] = {(const float*)d_in[2], (const float*)d_in[6],
                         (const float*)d_in[10], (const float*)d_in[14]};
  const float* bih[4] = {(const float*)d_in[3], (const float*)d_in[7],
                         (const float*)d_in[11], (const float*)d_in[15]};
  const float* bhh[4] = {(const float*)d_in[4], (const float*)d_in[8],
                         (const float*)d_in[12], (const float*)d_in[16]};
  const float* fc1_w = (const float*)d_in[17];
  const float* fc1_b = (const float*)d_in[18];
  const float* fc2_w = (const float*)d_in[19];
  const float* fc2_b = (const float*)d_in[20];

  char* ws = (char*)d_ws;
  size_t off = 0;
  auto alloc = [&](size_t bytes) -> char* {
    char* p = ws + off;
    off += (bytes + 255) & ~(size_t)255;
    return p;
  };

  h16* Cs[4];
  for (int l = 0; l < 4; l++) Cs[l] = (h16*)alloc((size_t)Bsz * 256 * 2);
  char* h10[2] = {alloc((size_t)Bsz * 512), alloc((size_t)Bsz * 512)};
  char* sl[2]  = {alloc((size_t)Bsz * 512), alloc((size_t)Bsz * 512)};
  char* h20[2] = {alloc((size_t)Bsz * 512), alloc((size_t)Bsz * 512)};
  char* h21[2] = {alloc((size_t)Bsz * 512), alloc((size_t)Bsz * 512)};
  float* pos = (float*)alloc((size_t)Bsz * 2 * 4);
  float* biasc = (float*)alloc(4 * 1024 * 4);
  h16* wp10 = (h16*)alloc((size_t)1024 * 256 * 2);
  h16* wp[3];
  for (int i = 0; i < 3; i++) wp[i] = (h16*)alloc((size_t)1024 * 512 * 2);
  h16* wpf1 = (h16*)alloc((size_t)256 * 256 * 2);

  if (ws_size < off) {
    mark_r16<<<dim3(1), dim3(64), 0, stream>>>((float*)d_out);
    return;
  }

  // ---- fused setup: packs + biases + pos + l0t0 ----
  {
    SetupArgs s;
    s.wp10 = wp10; s.wp0 = wp[0]; s.wp1 = wp[1]; s.wp2 = wp[2]; s.wpf1 = wpf1;
    s.biasc = biasc;
    s.Whh0 = Whh[0];
    s.Wih1 = Wih[1]; s.Whh1 = Whh[1];
    s.Wih2 = Wih[2]; s.Whh2 = Whh[2];
    s.Wih3 = Wih[3]; s.Whh3 = Whh[3];
    s.fc1w = fc1_w;
    s.bih0 = bih[0]; s.bhh0 = bhh[0];
    s.bih1 = bih[1]; s.bhh1 = bhh[1];
    s.bih2 = bih[2]; s.bhh2 = bhh[2];
    s.bih3 = bih[3]; s.bhh3 = bhh[3];
    s.x = x; s.Wih0 = Wih[0];
    s.pos = pos;
    s.C0 = Cs[0]; s.h00 = h10[0];
    setup_all<<<dim3(SO8 / 256), dim3(256), 0, stream>>>(s);
  }

  // ---- encoder: diagonal-fused launches, d = 1..10 (d=0 done in setup) ----
  char* hbuf[4][2] = {{h10[0], h10[1]}, {sl[0], sl[1]}, {h20[0], h20[1]}, {h21[0], h21[1]}};
  const h16* wpl[4] = {wp10, wp[0], wp[1], wp[2]};
  for (int d = 1; d <= 10; d++) {
    Fused4 args;
    int nc = 0;
    for (int l = 0; l < 4; l++) {
      int t = d - l;
      if (t < 0 || t >= Tseq) continue;
      CellDesc& cd = args.c[nc++];
      cd.A0 = (l == 0) ? hbuf[0][(t - 1) & 1] : hbuf[l - 1][t & 1];
      cd.A1 = (l > 0 && t > 0) ? hbuf[l][(t - 1) & 1] : cd.A0;
      cd.Wp = (const char*)wpl[l];
      cd.bias = biasc + l * 1024;
      cd.wih0 = (l == 0) ? Wih[0] : nullptr;
      cd.xbase = (l == 0) ? (x + t * 2) : nullptr;
      cd.Cst = Cs[l];
      cd.hout = hbuf[l][t & 1];
      cd.KBiter = (l == 0 || t == 0) ? 4 : 8;
      cd.KBpack = (l == 0) ? 4 : 8;     // slab stride matches pack-time KB
      cd.xstride = 16;
      cd.hasx = (l == 0) ? 1 : 0;
      cd.skipc = (t == 0) ? 1 : 0;
    }
    cells_diag<<<dim3(nc * 512), dim3(512), 0, stream>>>(args);
  }

  // ---- decoder ----
  int maxb = 0;
  hipError_t oe = hipOccupancyMaxActiveBlocksPerMultiprocessor(&maxb, decoder_coop, 512, 0);
  bool useCoop = (oe == hipSuccess && maxb >= 2);

  if (useCoop) {
    DecArgs da;
    da.hb0[0] = h10[0]; da.hb0[1] = h10[1];
    da.hb1[0] = sl[0];  da.hb1[1] = sl[1];
    da.hb2[0] = h20[0]; da.hb2[1] = h20[1];
    da.hb3[0] = h21[0]; da.hb3[1] = h21[1];
    da.Cs0 = Cs[0]; da.Cs1 = Cs[1]; da.Cs2 = Cs[2]; da.Cs3 = Cs[3];
    da.wp10 = (const char*)wp10; da.wp0 = (const char*)wp[0];
    da.wp1 = (const char*)wp[1]; da.wp2 = (const char*)wp[2];
    da.wpf1 = (const char*)wpf1;
    da.biasc = biasc; da.wih0 = Wih[0];
    da.fc1_b = fc1_b; da.fc2_w = fc2_w; da.fc2_b = fc2_b;
    da.pos = pos; da.out = (float*)d_out;
    void* kargs[] = { &da };
    hipError_t le = hipLaunchCooperativeKernel(decoder_coop, dim3(512), dim3(512),
                                               kargs, 0, stream);
    if (le == hipSuccess) return;
  }

  for (int s = 0; s < NPRED; s++) {
    int u = Tseq + s, cur = u & 1, prev = cur ^ 1;
    cell_gemm<1, 1><<<dim3(512), dim3(512), 0, stream>>>(
        h10[prev], h10[prev], (const char*)wp10, 256, biasc, Wih[0], pos, 2, Cs[0], h10[cur]);
    cell_gemm<2, 0><<<dim3(512), dim3(512), 0, stream>>>(
        h10[cur], sl[prev], (const char*)wp[0], 512, biasc + 1024, nullptr, nullptr, 0, Cs[1], sl[cur]);
    cell_gemm<2, 0><<<dim3(512), dim3(512), 0, stream>>>(
        sl[cur], h20[prev], (const char*)wp[1], 512, biasc + 2048, nullptr, nullptr, 0, Cs[2], h20[cur]);
    cell_gemm<2, 0><<<dim3(512), dim3(512), 0, stream>>>(
        h20[cur], h21[prev], (const char*)wp[2], 512, biasc + 3072, nullptr, nullptr, 0, Cs[3], h21[cur]);
    fc_head<<<dim3(128), dim3(512), 0, stream>>>(
        h21[cur], (const char*)wpf1, fc1_b, fc2_w, fc2_b, pos, (float*)d_out, s);
  }
}

// Round 21
// 2240.325 us; speedup vs baseline: 1.0114x; 1.0114x over previous
//
#include <hip/hip_runtime.h>
#include <hip/hip_cooperative_groups.h>
#include <stdint.h>

namespace cg = cooperative_groups;

// ====== TrajectoryLSTM r21 — r20 + per-by-slice pos copies (drop 12 grid.syncs) ======
#define Bsz   16384
#define Tseq  8
#define NPRED 12

typedef __attribute__((ext_vector_type(4))) float    f32x4;
typedef _Float16 h16;
typedef __attribute__((ext_vector_type(8))) _Float16 h16x8;

__device__ __forceinline__ float sigf(float x)   { return 1.f / (1.f + __expf(-x)); }
__device__ __forceinline__ float tanh_f(float x) { return 1.f - 2.f / (__expf(2.f * x) + 1.f); }

__device__ __forceinline__ void gload_lds16(const void* g, void* l) {
  __builtin_amdgcn_global_load_lds(
      (const __attribute__((address_space(1))) void*)g,
      (__attribute__((address_space(3))) void*)l, 16, 0, 0);
}

__global__ void mark_r21(float* __restrict__ out) {
  if (blockIdx.x == 0 && threadIdx.x < 64) out[threadIdx.x] = 1000.0f;
}

// ---- weight packing (device fn): slab-major [nb*KB+kb] blocks of [256 r][64 k]
// (32KB), XOR-preswizzled rows; gatePack: r -> n = gi*256 + nb*64 + wc*16 + jr.
__device__ __forceinline__ void pack_one(h16* dst, const float* W0, const float* W1,
                                         int ksplit, int Kw, int idx, int gatePack) {
  int np = idx / Kw, k = idx - np * Kw;
  int nb = np >> 8, r = np & 255;
  int n = np;
  if (gatePack) {
    int wcq = r >> 6, gi = (r >> 4) & 3, jr = r & 15;
    n = gi * 256 + nb * 64 + wcq * 16 + jr;
  }
  float w = (k < ksplit) ? W0[(size_t)n * ksplit + k]
                         : W1[(size_t)n * (Kw - ksplit) + (k - ksplit)];
  int KB = Kw >> 6, kb = k >> 6;
  uint32_t byte = (uint32_t)(nb * KB + kb) * 32768u + (uint32_t)r * 128u
                + ((2u * (uint32_t)(k & 63)) ^ (uint32_t)((r & 7) << 4));
  *(h16*)((char*)dst + byte) = (h16)w;
}

// ---- fused setup: packs + biases + pos seed (x4 copies) + L1.l0@t=0 pointwise ----
#define SO1 262144
#define SO2 786432
#define SO3 1310720
#define SO4 1835008
#define SO5 1900544
#define SO6 1904640
#define SO7 1970176
#define SO8 2494464

struct SetupArgs {
  h16 *wp10, *wp0, *wp1, *wp2, *wpf1;
  float* biasc;
  const float *Whh0, *Wih1, *Whh1, *Wih2, *Whh2, *Wih3, *Whh3, *fc1w;
  const float *bih0, *bhh0, *bih1, *bhh1, *bih2, *bhh2, *bih3, *bhh3;
  const float *x, *Wih0;
  float* pos;
  h16* C0; char* h00;
};

__global__ void setup_all(SetupArgs s) {
  int gid = blockIdx.x * 256 + threadIdx.x;
  if (gid < SO1) {
    pack_one(s.wp10, s.Whh0, s.Whh0, 256, 256, gid, 1);
  } else if (gid < SO2) {
    pack_one(s.wp0, s.Wih1, s.Whh1, 256, 512, gid - SO1, 1);
  } else if (gid < SO3) {
    pack_one(s.wp1, s.Wih2, s.Whh2, 256, 512, gid - SO2, 1);
  } else if (gid < SO4) {
    pack_one(s.wp2, s.Wih3, s.Whh3, 256, 512, gid - SO3, 1);
  } else if (gid < SO5) {
    pack_one(s.wpf1, s.fc1w, s.fc1w, 256, 256, gid - SO4, 0);
  } else if (gid < SO6) {
    int i = gid - SO5;
    int l = i >> 10, j = i & 1023;
    const float* bi_[4] = {s.bih0, s.bih1, s.bih2, s.bih3};
    const float* bh_[4] = {s.bhh0, s.bhh1, s.bhh2, s.bhh3};
    s.biasc[i] = bi_[l][j] + bh_[l][j];
  } else if (gid < SO7) {
    int b = gid - SO6;                 // 0 .. 4*Bsz-1 (4 contiguous pos copies)
    int br = b & (Bsz - 1);
    s.pos[2 * b]     = s.x[(size_t)br * 16 + 14];
    s.pos[2 * b + 1] = s.x[(size_t)br * 16 + 15];
  } else if (gid < SO8) {
    int t = gid - SO7;
    int b = t >> 5, jb = (t & 31) << 3;
    float x0 = s.x[(size_t)b * 16], x1 = s.x[(size_t)b * 16 + 1];
    h16 cc[8], hh[8];
#pragma unroll
    for (int q = 0; q < 8; ++q) {
      int j = jb + q;
      float vi = s.bih0[j]       + s.bhh0[j]       + x0 * s.Wih0[2 * j]         + x1 * s.Wih0[2 * j + 1];
      float vg = s.bih0[512 + j] + s.bhh0[512 + j] + x0 * s.Wih0[2 * (512 + j)] + x1 * s.Wih0[2 * (512 + j) + 1];
      float vo = s.bih0[768 + j] + s.bhh0[768 + j] + x0 * s.Wih0[2 * (768 + j)] + x1 * s.Wih0[2 * (768 + j) + 1];
      float cn = sigf(vi) * tanh_f(vg);
      hh[q] = (h16)(sigf(vo) * tanh_f(cn));
      cc[q] = (h16)cn;
    }
    *(h16x8*)(s.C0 + (size_t)b * 256 + jb) = *(h16x8*)cc;
    *(h16x8*)(s.h00 + (size_t)b * 512 + (((unsigned)jb * 2) ^ (unsigned)((b & 7) << 4))) = *(h16x8*)hh;
  }
}

// ---- GEMM core: 512 threads / 8 waves (2Mx4N), tile 128x256, BK=64 ----
__device__ __forceinline__ void gemm_core(
    const char* A0, const char* A1, const char* Wp, int KBiter, int KBpack,
    int by, int m0, char* lds, int tid, f32x4 acc[4][4]) {
  char* ldsA = lds;
  char* ldsB = lds + 16384;
  const int wave = tid >> 6, lane = tid & 63;
  const int wr = wave >> 2, wc = wave & 3;
  const int rowa = tid >> 3;          // 0..63
  const int chb  = (tid & 7) * 16;

#pragma unroll
  for (int m = 0; m < 4; m++)
#pragma unroll
    for (int n = 0; n < 4; n++)
#pragma unroll
      for (int e = 0; e < 4; e++) acc[m][n][e] = 0.f;

  const char* aCur   = A0 + (size_t)(m0 + rowa) * 512 + chb;
  const char* a1Base = A1 + (size_t)(m0 + rowa) * 512 + chb;
  const char* wCur   = Wp + (size_t)by * KBpack * 32768 + (size_t)tid * 16;

  for (int kb = 0; kb < KBiter; ++kb) {
    if (kb == 4) aCur = a1Base;       // K=512 segment switch (unreachable at KBiter==4)
    gload_lds16(aCur,          ldsA + wave * 1024);          // rows 0..63
    gload_lds16(aCur + 32768,  ldsA + 8192 + wave * 1024);   // rows 64..127
#pragma unroll
    for (int it = 0; it < 4; ++it)
      gload_lds16(wCur + it * 8192, ldsB + it * 8192 + wave * 1024);
    __syncthreads();
#pragma unroll
    for (int kk = 0; kk < 2; ++kk) {
      const int kbyte = kk * 64 + (lane >> 4) * 16;
      h16x8 af[4], bfr[4];
#pragma unroll
      for (int mt = 0; mt < 4; ++mt) {
        int r = wr * 64 + mt * 16 + (lane & 15);
        af[mt] = *(const h16x8*)(ldsA + r * 128 + (kbyte ^ ((r & 7) << 4)));
      }
#pragma unroll
      for (int nt = 0; nt < 4; ++nt) {
        int c = wc * 64 + nt * 16 + (lane & 15);
        bfr[nt] = *(const h16x8*)(ldsB + c * 128 + (kbyte ^ ((c & 7) << 4)));
      }
#pragma unroll
      for (int mt = 0; mt < 4; ++mt)
#pragma unroll
        for (int nt = 0; nt < 4; ++nt)
          acc[mt][nt] = __builtin_amdgcn_mfma_f32_16x16x32_f16(af[mt], bfr[nt], acc[mt][nt], 0, 0, 0);
    }
    __syncthreads();
    aCur += 128;
    wCur += 32768;
  }
}

// ---- LSTM epilogue: lane owns ONE j (= by*64 + wc*16 + lane&15); gates = nt ----
__device__ __forceinline__ void lstm_epilogue(
    f32x4 acc[4][4], int m0, int by, int tid, const float* bias,
    const float* wih0, const float* xbase, int xstride, int hasx, int skipc,
    h16* Cst, char* hout) {
  const int wave = tid >> 6, lane = tid & 63;
  const int wr = wave >> 2, wc = wave & 3;
  const int j = by * 64 + wc * 16 + (lane & 15);
  const float bi = bias[j], bff = bias[256 + j], bg = bias[512 + j], bo = bias[768 + j];
  float wi0 = 0, wi1 = 0, wf0 = 0, wf1 = 0, wg0 = 0, wg1 = 0, wo0 = 0, wo1 = 0;
  if (hasx) {
    wi0 = wih0[2 * j];           wi1 = wih0[2 * j + 1];
    wf0 = wih0[2 * (256 + j)];   wf1 = wih0[2 * (256 + j) + 1];
    wg0 = wih0[2 * (512 + j)];   wg1 = wih0[2 * (512 + j) + 1];
    wo0 = wih0[2 * (768 + j)];   wo1 = wih0[2 * (768 + j) + 1];
  }
#pragma unroll
  for (int mt = 0; mt < 4; ++mt) {
#pragma unroll
    for (int e = 0; e < 4; e++) {
      const int b = m0 + wr * 64 + mt * 16 + (lane >> 4) * 4 + e;
      float vi = acc[mt][0][e] + bi;
      float vf = acc[mt][1][e] + bff;
      float vg = acc[mt][2][e] + bg;
      float vo = acc[mt][3][e] + bo;
      if (hasx) {
        const float x0 = xbase[(size_t)b * xstride];
        const float x1 = xbase[(size_t)b * xstride + 1];
        vi += x0 * wi0 + x1 * wi1;
        vf += x0 * wf0 + x1 * wf1;
        vg += x0 * wg0 + x1 * wg1;
        vo += x0 * wo0 + x1 * wo1;
      }
      const size_t ci = (size_t)b * 256 + j;
      float cn = sigf(vi) * tanh_f(vg);
      if (!skipc) cn += sigf(vf) * (float)Cst[ci];
      float h = sigf(vo) * tanh_f(cn);
      Cst[ci] = (h16)cn;
      *(h16*)(hout + (size_t)b * 512 + (((unsigned)j * 2) ^ (unsigned)((b & 7) << 4))) = (h16)h;
    }
  }
}

// ---- fused fc1+relu+fc2+pos body: ONE K=256 N=256 GEMM + strip + dot ----
__device__ __forceinline__ void head_body(
    const char* A, const char* Wp, const float* b1, const float* w2,
    const float* b2, float* pos, float* out, int s, int blk, int tid, char* lds) {
  const int m0 = blk * 128;
  const int wave = tid >> 6, lane = tid & 63;
  const int wr = wave >> 2, wc = wave & 3;

  f32x4 acc[4][4];
  gemm_core(A, A, Wp, 4, 4, 0, m0, lds, tid, acc);

  h16* strip = (h16*)lds;    // [128][262] fp16 = 67072 B
#pragma unroll
  for (int nt = 0; nt < 4; ++nt) {
    const int n = wc * 64 + nt * 16 + (lane & 15);
    const float bn = b1[n];
#pragma unroll
    for (int mt = 0; mt < 4; ++mt)
#pragma unroll
      for (int e = 0; e < 4; e++) {
        const int bl = wr * 64 + mt * 16 + (lane >> 4) * 4 + e;
        float v = acc[mt][nt][e] + bn;
        strip[bl * 262 + n] = (h16)(v > 0.f ? v : 0.f);
      }
  }
  __syncthreads();
  if (tid < 256) {
    const int bl2 = tid >> 1, comp = tid & 1;
    const float* wrow = w2 + comp * 256;
    float a = 0.f;
#pragma unroll 8
    for (int n = 0; n < 256; ++n)
      a += (float)strip[bl2 * 262 + n] * wrow[n];
    const size_t b = (size_t)(m0 + bl2);
    float p = pos[2 * b + comp] + a + b2[comp];
    pos[2 * b + comp] = p;
    out[b * (NPRED * 2) + s * 2 + comp] = p;
  }
  __syncthreads();
}

// ---- per-cell descriptor (encoder diagonals) ----
struct CellDesc {
  const char* A0; const char* A1; const char* Wp;
  const float* bias; const float* wih0; const float* xbase;
  h16* Cst; char* hout;
  int KBiter; int KBpack; int xstride; int hasx; int skipc;
};
struct Fused4 { CellDesc c[4]; };

__global__ __launch_bounds__(512, 4) void cells_diag(Fused4 args) {
  const int cellid = blockIdx.x >> 9;
  const int lid    = blockIdx.x & 511;
  const CellDesc d = args.c[cellid];

  __shared__ __align__(16) char lds[49152];
  const int tid = threadIdx.x;

  int swz = (lid & 7) * 64 + (lid >> 3);
  const int by = swz & 3, bx = swz >> 2;   // NY = 4
  const int m0 = bx * 128;

  f32x4 acc[4][4];
  gemm_core(d.A0, d.A1, d.Wp, d.KBiter, d.KBpack, by, m0, lds, tid, acc);
  lstm_epilogue(acc, m0, by, tid, d.bias, d.wih0, d.xbase, d.xstride, d.hasx,
                d.skipc, d.Cst, d.hout);
}

// ---- decoder args + cooperative persistent kernel (512 blocks = 2/CU) ----
struct DecArgs {
  char* hb0[2]; char* hb1[2]; char* hb2[2]; char* hb3[2];
  h16* Cs0; h16* Cs1; h16* Cs2; h16* Cs3;
  const char* wp10; const char* wp0; const char* wp1; const char* wp2; const char* wpf1;
  const float* biasc; const float* wih0;
  const float* fc1_b; const float* fc2_w; const float* fc2_b;
  float* pos; float* out;
};

__global__ __launch_bounds__(512, 4) void decoder_coop(DecArgs a) {
  cg::grid_group grid = cg::this_grid();
  __shared__ __align__(16) char lds[67072];
  const int tid = threadIdx.x;
  const int lid = blockIdx.x;
  int swz = (lid & 7) * 64 + (lid >> 3);
  const int by = swz & 3, bx = swz >> 2;
  const int m0 = bx * 128;
  // per-by-slice pos copy: identical arithmetic in all 4 copies, no cross-copy RMW
  float* posb = a.pos + (size_t)by * Bsz * 2;

  for (int s = 0; s < NPRED; ++s) {
    const int u = Tseq + s, cur = u & 1, prev = cur ^ 1;
    {  // L1.l0 (K=256, x-part = own pos copy)
      f32x4 acc[4][4];
      gemm_core(a.hb0[prev], a.hb0[prev], a.wp10, 4, 4, by, m0, lds, tid, acc);
      lstm_epilogue(acc, m0, by, tid, a.biasc, a.wih0, posb, 2, 1, 0, a.Cs0, a.hb0[cur]);
    }
    __threadfence();  grid.sync();
    {  // L1.l1 (K=512)
      f32x4 acc[4][4];
      gemm_core(a.hb0[cur], a.hb1[prev], a.wp0, 8, 8, by, m0, lds, tid, acc);
      lstm_epilogue(acc, m0, by, tid, a.biasc + 1024, nullptr, nullptr, 0, 0, 0, a.Cs1, a.hb1[cur]);
    }
    __threadfence();  grid.sync();
    {  // L2.l0 (K=512)
      f32x4 acc[4][4];
      gemm_core(a.hb1[cur], a.hb2[prev], a.wp1, 8, 8, by, m0, lds, tid, acc);
      lstm_epilogue(acc, m0, by, tid, a.biasc + 2048, nullptr, nullptr, 0, 0, 0, a.Cs2, a.hb2[cur]);
    }
    __threadfence();  grid.sync();
    {  // L2.l1 (K=512)
      f32x4 acc[4][4];
      gemm_core(a.hb2[cur], a.hb3[prev], a.wp2, 8, 8, by, m0, lds, tid, acc);
      lstm_epilogue(acc, m0, by, tid, a.biasc + 3072, nullptr, nullptr, 0, 0, 0, a.Cs3, a.hb3[cur]);
    }
    __threadfence();  grid.sync();
    // head: ALL blocks, redundant per stripe against own pos copy (identical
    // fp32 values; benign identical out-writes). No trailing grid.sync —
    // next L1.l0 reads only own-block pos writes (ordered by syncthreads).
    head_body(a.hb3[cur], a.wpf1, a.fc1_b, a.fc2_w, a.fc2_b, posb, a.out, s, bx, tid, lds);
    __threadfence();
  }
}

// ---- fallback decoder kernels ----
template <int NSEG, int HASX>
__global__ __launch_bounds__(512, 4) void cell_gemm(
    const char* __restrict__ A0, const char* __restrict__ A1,
    const char* __restrict__ Wp, int Kw,
    const float* __restrict__ bias, const float* __restrict__ wih0,
    const float* __restrict__ xbase, int xstride,
    h16* __restrict__ Cst, char* __restrict__ hout) {
  __shared__ __align__(16) char lds[49152];
  const int tid = threadIdx.x;
  int lid = blockIdx.x;
  int swz = (lid & 7) * 64 + (lid >> 3);
  const int by = swz & 3, bx = swz >> 2;
  const int m0 = bx * 128;
  f32x4 acc[4][4];
  gemm_core(A0, NSEG == 2 ? A1 : A0, Wp, Kw >> 6, Kw >> 6, by, m0, lds, tid, acc);
  lstm_epilogue(acc, m0, by, tid, bias, wih0, xbase, xstride, HASX, 0, Cst, hout);
}

__global__ __launch_bounds__(512) void fc_head(
    const char* __restrict__ A, const char* __restrict__ Wp,
    const float* __restrict__ b1, const float* __restrict__ w2,
    const float* __restrict__ b2, float* __restrict__ pos,
    float* __restrict__ out, int s) {
  __shared__ __align__(16) char lds[67072];
  head_body(A, Wp, b1, w2, b2, pos, out, s, blockIdx.x, threadIdx.x, lds);
}

// ---------- host ----------
extern "C" void kernel_launch(void* const* d_in, const int* in_sizes, int n_in,
                              void* d_out, int out_size, void* d_ws, size_t ws_size,
                              hipStream_t stream) {
  const float* x      = (const float*)d_in[0];
  const float* Wih[4] = {(const float*)d_in[1], (const float*)d_in[5],
                         (const float*)d_in[9], (const float*)d_in[13]};
  const float* Whh[4] = {(const float*)d_in[2], (const float*)d_in[6],
                         (const float*)d_in[10], (const float*)d_in[14]};
  const float* bih[4] = {(const float*)d_in[3], (const float*)d_in[7],
                         (const float*)d_in[11], (const float*)d_in[15]};
  const float* bhh[4] = {(const float*)d_in[4], (const float*)d_in[8],
                         (const float*)d_in[12], (const float*)d_in[16]};
  const float* fc1_w = (const float*)d_in[17];
  const float* fc1_b = (const float*)d_in[18];
  const float* fc2_w = (const float*)d_in[19];
  const float* fc2_b = (const float*)d_in[20];

  char* ws = (char*)d_ws;
  size_t off = 0;
  auto alloc = [&](size_t bytes) -> char* {
    char* p = ws + off;
    off += (bytes + 255) & ~(size_t)255;
    return p;
  };

  h16* Cs[4];
  for (int l = 0; l < 4; l++) Cs[l] = (h16*)alloc((size_t)Bsz * 256 * 2);
  char* h10[2] = {alloc((size_t)Bsz * 512), alloc((size_t)Bsz * 512)};
  char* sl[2]  = {alloc((size_t)Bsz * 512), alloc((size_t)Bsz * 512)};
  char* h20[2] = {alloc((size_t)Bsz * 512), alloc((size_t)Bsz * 512)};
  char* h21[2] = {alloc((size_t)Bsz * 512), alloc((size_t)Bsz * 512)};
  float* pos = (float*)alloc((size_t)4 * Bsz * 2 * 4);   // 4 per-by-slice copies
  float* biasc = (float*)alloc(4 * 1024 * 4);
  h16* wp10 = (h16*)alloc((size_t)1024 * 256 * 2);
  h16* wp[3];
  for (int i = 0; i < 3; i++) wp[i] = (h16*)alloc((size_t)1024 * 512 * 2);
  h16* wpf1 = (h16*)alloc((size_t)256 * 256 * 2);

  if (ws_size < off) {
    mark_r21<<<dim3(1), dim3(64), 0, stream>>>((float*)d_out);
    return;
  }

  // ---- fused setup: packs + biases + pos(x4) + l0t0 ----
  {
    SetupArgs s;
    s.wp10 = wp10; s.wp0 = wp[0]; s.wp1 = wp[1]; s.wp2 = wp[2]; s.wpf1 = wpf1;
    s.biasc = biasc;
    s.Whh0 = Whh[0];
    s.Wih1 = Wih[1]; s.Whh1 = Whh[1];
    s.Wih2 = Wih[2]; s.Whh2 = Whh[2];
    s.Wih3 = Wih[3]; s.Whh3 = Whh[3];
    s.fc1w = fc1_w;
    s.bih0 = bih[0]; s.bhh0 = bhh[0];
    s.bih1 = bih[1]; s.bhh1 = bhh[1];
    s.bih2 = bih[2]; s.bhh2 = bhh[2];
    s.bih3 = bih[3]; s.bhh3 = bhh[3];
    s.x = x; s.Wih0 = Wih[0];
    s.pos = pos;
    s.C0 = Cs[0]; s.h00 = h10[0];
    setup_all<<<dim3(SO8 / 256), dim3(256), 0, stream>>>(s);
  }

  // ---- encoder: diagonal-fused launches, d = 1..10 (d=0 done in setup) ----
  char* hbuf[4][2] = {{h10[0], h10[1]}, {sl[0], sl[1]}, {h20[0], h20[1]}, {h21[0], h21[1]}};
  const h16* wpl[4] = {wp10, wp[0], wp[1], wp[2]};
  for (int d = 1; d <= 10; d++) {
    Fused4 args;
    int nc = 0;
    for (int l = 0; l < 4; l++) {
      int t = d - l;
      if (t < 0 || t >= Tseq) continue;
      CellDesc& cd = args.c[nc++];
      cd.A0 = (l == 0) ? hbuf[0][(t - 1) & 1] : hbuf[l - 1][t & 1];
      cd.A1 = (l > 0 && t > 0) ? hbuf[l][(t - 1) & 1] : cd.A0;
      cd.Wp = (const char*)wpl[l];
      cd.bias = biasc + l * 1024;
      cd.wih0 = (l == 0) ? Wih[0] : nullptr;
      cd.xbase = (l == 0) ? (x + t * 2) : nullptr;
      cd.Cst = Cs[l];
      cd.hout = hbuf[l][t & 1];
      cd.KBiter = (l == 0 || t == 0) ? 4 : 8;
      cd.KBpack = (l == 0) ? 4 : 8;     // slab stride matches pack-time KB
      cd.xstride = 16;
      cd.hasx = (l == 0) ? 1 : 0;
      cd.skipc = (t == 0) ? 1 : 0;
    }
    cells_diag<<<dim3(nc * 512), dim3(512), 0, stream>>>(args);
  }

  // ---- decoder ----
  int maxb = 0;
  hipError_t oe = hipOccupancyMaxActiveBlocksPerMultiprocessor(&maxb, decoder_coop, 512, 0);
  bool useCoop = (oe == hipSuccess && maxb >= 2);

  if (useCoop) {
    DecArgs da;
    da.hb0[0] = h10[0]; da.hb0[1] = h10[1];
    da.hb1[0] = sl[0];  da.hb1[1] = sl[1];
    da.hb2[0] = h20[0]; da.hb2[1] = h20[1];
    da.hb3[0] = h21[0]; da.hb3[1] = h21[1];
    da.Cs0 = Cs[0]; da.Cs1 = Cs[1]; da.Cs2 = Cs[2]; da.Cs3 = Cs[3];
    da.wp10 = (const char*)wp10; da.wp0 = (const char*)wp[0];
    da.wp1 = (const char*)wp[1]; da.wp2 = (const char*)wp[2];
    da.wpf1 = (const char*)wpf1;
    da.biasc = biasc; da.wih0 = Wih[0];
    da.fc1_b = fc1_b; da.fc2_w = fc2_w; da.fc2_b = fc2_b;
    da.pos = pos; da.out = (float*)d_out;
    void* kargs[] = { &da };
    hipError_t le = hipLaunchCooperativeKernel(decoder_coop, dim3(512), dim3(512),
                                               kargs, 0, stream);
    if (le == hipSuccess) return;
  }

  for (int s = 0; s < NPRED; s++) {
    int u = Tseq + s, cur = u & 1, prev = cur ^ 1;
    cell_gemm<1, 1><<<dim3(512), dim3(512), 0, stream>>>(
        h10[prev], h10[prev], (const char*)wp10, 256, biasc, Wih[0], pos, 2, Cs[0], h10[cur]);
    cell_gemm<2, 0><<<dim3(512), dim3(512), 0, stream>>>(
        h10[cur], sl[prev], (const char*)wp[0], 512, biasc + 1024, nullptr, nullptr, 0, Cs[1], sl[cur]);
    cell_gemm<2, 0><<<dim3(512), dim3(512), 0, stream>>>(
        sl[cur], h20[prev], (const char*)wp[1], 512, biasc + 2048, nullptr, nullptr, 0, Cs[2], h20[cur]);
    cell_gemm<2, 0><<<dim3(512), dim3(512), 0, stream>>>(
        h20[cur], h21[prev], (const char*)wp[2], 512, biasc + 3072, nullptr, nullptr, 0, Cs[3], h21[cur]);
    fc_head<<<dim3(128), dim3(512), 0, stream>>>(
        h21[cur], (const char*)wpf1, fc1_b, fc2_w, fc2_b, pos, (float*)d_out, s);
  }
}